// Round 1
// baseline (339.562 us; speedup 1.0000x reference)
//
#include <hip/hip_runtime.h>
#include <cstdint>

#define T_STEPS 16384

// ---- workspace float offsets ----
#define WS_U    0         // 256
#define WS_V    256       // 256
#define WS_UDC  512       // 128
#define WS_VDC  640       // 128
#define WS_A    768       // 64
#define WS_PEN  832       // 64
#define WS_W4T  896       // 512 (64x8)
#define WS_D3T  1408      // 512 (64x8)
#define WS_W2T  2048      // 32768 (256x128)
#define WS_W3T  34816     // 8192  (128x64)
#define WS_D2T  43008     // 8192  (128x64)
#define WS_DV   51200     // 131072 (16384x8)
#define WS_CONS 182272    // 1048576 (16384x8x8)
#define WS_END_F 1230848
// byte offsets after the float region
#define WSB_NXT8 (WS_END_F * 4)          // 131072 bytes (u8 nxt[t][c])
#define WSB_CUR  (WSB_NXT8 + 131072)     // 65536 bytes (u32 cur[t])

__device__ __forceinline__ unsigned int fn_compose(unsigned int hi, unsigned int lo) {
  // (hi o lo)(x) = hi[lo[x]], 8 states x 3 bits packed in u32
  unsigned int r = 0;
  #pragma unroll
  for (int x = 0; x < 8; ++x) {
    unsigned int m = (lo >> (3 * x)) & 7u;
    r |= ((hi >> (3 * m)) & 7u) << (3 * x);
  }
  return r;
}

// ---------------- setup: u,v,udc,vdc,A,pen,W4T,D3T ----------------
__global__ void k_setup(const float* __restrict__ pa, const float* __restrict__ W1,
                        const float* __restrict__ b1, const float* __restrict__ D1,
                        const float* __restrict__ d1, const float* __restrict__ W4,
                        const float* __restrict__ D3, const int* __restrict__ edge,
                        float* __restrict__ ws) {
  int tid = threadIdx.x;  // 256
  {
    int k = tid;
    float acc = b1[k];
    #pragma unroll
    for (int i = 0; i < 8; ++i) acc = fmaf(pa[i], W1[k * 17 + i], acc);
    ws[WS_U + k] = acc;
    ws[WS_V + k] = W1[k * 17 + 8];
  }
  if (tid < 128) {
    float acc = d1[tid];
    #pragma unroll
    for (int i = 0; i < 8; ++i) acc = fmaf(pa[i], D1[tid * 9 + i], acc);
    ws[WS_UDC + tid] = acc;
    ws[WS_VDC + tid] = D1[tid * 9 + 8];
  }
  if (tid < 64) ws[WS_A + tid] = ((tid >> 3) == (tid & 7)) ? 1.0f : 0.0f;
  for (int idx = tid; idx < 512; idx += 256) {
    int k = idx >> 3, z = idx & 7;
    ws[WS_W4T + idx] = W4[z * 64 + k];
    ws[WS_D3T + idx] = D3[z * 64 + k];
  }
  __syncthreads();
  if (tid == 0) {
    for (int e = 0; e < 16; ++e) {
      int a = edge[e], b = edge[16 + e];
      ws[WS_A + a * 8 + b] = 1.0f;
      ws[WS_A + b * 8 + a] = 1.0f;
    }
  }
  __syncthreads();
  if (tid < 64) ws[WS_PEN + tid] = 1000.0f * (1.0f - ws[WS_A + tid]);
}

// ---------------- transposes: W2T, W3T, D2T ----------------
__global__ void k_transpose(const float* __restrict__ W2, const float* __restrict__ W3,
                            const float* __restrict__ D2, float* __restrict__ ws) {
  int idx = blockIdx.x * 256 + threadIdx.x;
  if (idx < 32768) {
    int j = idx >> 8, k = idx & 255;
    ws[WS_W2T + k * 128 + j] = W2[idx];
  } else if (idx < 40960) {
    int i = idx - 32768;
    int j = i >> 7, k = i & 127;
    ws[WS_W3T + k * 64 + j] = W3[i];
  } else if (idx < 49152) {
    int i = idx - 40960;
    int j = i >> 7, k = i & 127;
    ws[WS_D2T + k * 64 + j] = D2[i];
  }
}

// ---------------- diversity network: dv[t][8] ----------------
__global__ void __launch_bounds__(256) k_diversity(
    const float* __restrict__ times, const float* __restrict__ d2,
    const float* __restrict__ d3, float* __restrict__ ws) {
  __shared__ float h1dT[128][64];  // 32KB
  __shared__ float h2dT[64][64];   // 16KB
  int tid = threadIdx.x;
  int s = tid & 63, w = tid >> 6;   // lane=t-sample, 4 waves
  int t = blockIdx.x * 64 + s;
  float last = times[T_STEPS - 1];
  float st = (last > 0.0f) ? times[t] / last : 0.0f;
  int j0 = __builtin_amdgcn_readfirstlane(w * 32);
  #pragma unroll
  for (int jj = 0; jj < 32; ++jj) {
    int j = j0 + jj;
    h1dT[j][s] = fmaxf(fmaf(st, ws[WS_VDC + j], ws[WS_UDC + j]), 0.0f);
  }
  __syncthreads();
  j0 = __builtin_amdgcn_readfirstlane(w * 16);
  float acc[16];
  #pragma unroll
  for (int jj = 0; jj < 16; ++jj) acc[jj] = d2[j0 + jj];
  #pragma unroll 4
  for (int k = 0; k < 128; ++k) {
    float h = h1dT[k][s];
    #pragma unroll
    for (int jj = 0; jj < 16; ++jj)
      acc[jj] = fmaf(ws[WS_D2T + k * 64 + j0 + jj], h, acc[jj]);
  }
  #pragma unroll
  for (int jj = 0; jj < 16; ++jj) h2dT[j0 + jj][s] = fmaxf(acc[jj], 0.0f);
  __syncthreads();
  if (tid < 64) {
    float a8[8];
    #pragma unroll
    for (int z = 0; z < 8; ++z) a8[z] = d3[z];
    #pragma unroll 4
    for (int k = 0; k < 64; ++k) {
      float h = h2dT[k][s];
      #pragma unroll
      for (int z = 0; z < 8; ++z) a8[z] = fmaf(ws[WS_D3T + k * 8 + z], h, a8[z]);
    }
    #pragma unroll
    for (int z = 0; z < 8; ++z) ws[WS_DV + t * 8 + z] = tanhf(a8[z]);
  }
}

// ---------------- phase B: all (t, c) MLP evals ----------------
__global__ void __launch_bounds__(512) k_phaseB(
    const float* __restrict__ times, const float* __restrict__ W1,
    const float* __restrict__ b2, const float* __restrict__ b3,
    const float* __restrict__ b4, const float* __restrict__ gum,
    const float* __restrict__ tau, float* __restrict__ ws) {
  extern __shared__ float lds[];
  float* h1T = lds;            // [256][64] stride-64: bank = s%32, 2-way (free)
  float* h2T = lds + 16384;    // [128][64]
  int tid = threadIdx.x;
  int s = tid & 63, w = tid >> 6;  // lane = sample (tt*8 + c), 8 waves
  int t0 = blockIdx.x * 8;
  int t = t0 + (s >> 3);
  int c = s & 7;
  float last = times[T_STEPS - 1];
  float st = (last > 0.0f) ? times[t] / last : 0.0f;

  // layer 1: h1 = relu(u + st*v + W1z[:,c]); wave w fills k in [w*32, w*32+32)
  int k0 = __builtin_amdgcn_readfirstlane(w * 32);
  #pragma unroll
  for (int kk = 0; kk < 32; ++kk) {
    int k = k0 + kk;
    float v = fmaf(st, ws[WS_V + k], ws[WS_U + k]) + W1[k * 17 + 9 + c];
    h1T[k * 64 + s] = fmaxf(v, 0.0f);
  }
  __syncthreads();

  // layer 2: 128 outputs; wave w: j in [w*16, +16); W2T via scalar loads
  int j0 = __builtin_amdgcn_readfirstlane(w * 16);
  float acc[16];
  #pragma unroll
  for (int jj = 0; jj < 16; ++jj) acc[jj] = b2[j0 + jj];
  #pragma unroll 4
  for (int k = 0; k < 256; ++k) {
    float h = h1T[k * 64 + s];
    #pragma unroll
    for (int jj = 0; jj < 16; ++jj)
      acc[jj] = fmaf(ws[WS_W2T + k * 128 + j0 + jj], h, acc[jj]);
  }
  #pragma unroll
  for (int jj = 0; jj < 16; ++jj) h2T[(j0 + jj) * 64 + s] = fmaxf(acc[jj], 0.0f);
  __syncthreads();

  // layer 3: 64 outputs; wave w: j in [w*8, +8); h3 aliased into h1T rows 0..63
  j0 = __builtin_amdgcn_readfirstlane(w * 8);
  float a3[8];
  #pragma unroll
  for (int i = 0; i < 8; ++i) a3[i] = b3[j0 + i];
  #pragma unroll 4
  for (int k = 0; k < 128; ++k) {
    float h = h2T[k * 64 + s];
    #pragma unroll
    for (int i = 0; i < 8; ++i)
      a3[i] = fmaf(ws[WS_W3T + k * 64 + j0 + i], h, a3[i]);
  }
  #pragma unroll
  for (int i = 0; i < 8; ++i) h1T[(j0 + i) * 64 + s] = fmaxf(a3[i], 0.0f);
  __syncthreads();

  // layer 4 + epilogue: wave 0 only (lane = sample)
  if (tid < 64) {
    float a4[8];
    #pragma unroll
    for (int z = 0; z < 8; ++z) a4[z] = b4[z];
    #pragma unroll 4
    for (int k = 0; k < 64; ++k) {
      float h = h1T[k * 64 + s];  // h3
      #pragma unroll
      for (int z = 0; z < 8; ++z)
        a4[z] = fmaf(ws[WS_W4T + k * 8 + z], h, a4[z]);
    }
    float tauv = tau[0];
    float cons[8];
    float best = 0.0f;
    int bi = 0;
    #pragma unroll
    for (int z = 0; z < 8; ++z) {
      float lg = fmaf(0.2f, ws[WS_DV + t * 8 + z], a4[z]) - ws[WS_PEN + c * 8 + z];
      cons[z] = lg;
      float uu = gum[t * 8 + z];
      float g = -logf(-logf(uu + 1e-20f) + 1e-20f);
      float y = (lg + g) / tauv;
      if (z == 0) { best = y; bi = 0; }
      else if (y > best) { best = y; bi = z; }   // first-index tie-break like jnp.argmax
    }
    float4* cp = (float4*)(ws + WS_CONS + (t * 8 + c) * 8);
    cp[0] = make_float4(cons[0], cons[1], cons[2], cons[3]);
    cp[1] = make_float4(cons[4], cons[5], cons[6], cons[7]);
    unsigned char* nxt8 = (unsigned char*)ws + WSB_NXT8;
    nxt8[t0 * 8 + s] = (unsigned char)bi;
  }
}

// ---------------- phase C: parallel prefix over transition functions ----------------
__global__ void __launch_bounds__(256) k_phaseC(float* __restrict__ ws, float* __restrict__ d_out) {
  int tid = threadIdx.x;
  const unsigned char* nxt8 = (const unsigned char*)ws + WSB_NXT8;
  unsigned int* cur_arr = (unsigned int*)((char*)ws + WSB_CUR);
  const unsigned int IDENT = 0x00FAC688u;  // identity map: x at bits 3x
  unsigned int f[64];
  int t0 = tid * 64;
  unsigned int F = IDENT;
  #pragma unroll
  for (int i = 0; i < 64; ++i) {
    uint2 b = *(const uint2*)(nxt8 + (size_t)(t0 + i) * 8);
    unsigned int fn = 0;
    #pragma unroll
    for (int q = 0; q < 4; ++q) fn |= ((b.x >> (8 * q)) & 7u) << (3 * q);
    #pragma unroll
    for (int q = 0; q < 4; ++q) fn |= ((b.y >> (8 * q)) & 7u) << (3 * (q + 4));
    f[i] = fn;
    F = fn_compose(fn, F);
  }
  __shared__ unsigned int sc[256];
  sc[tid] = F;
  __syncthreads();
  #pragma unroll
  for (int d = 1; d < 256; d <<= 1) {
    unsigned int v = sc[tid];
    unsigned int p = (tid >= d) ? sc[tid - d] : 0u;
    unsigned int nv = (tid >= d) ? fn_compose(v, p) : v;
    __syncthreads();
    sc[tid] = nv;
    __syncthreads();
  }
  unsigned int E = (tid == 0) ? IDENT : sc[tid - 1];
  unsigned int state = E & 7u;
  #pragma unroll
  for (int i = 0; i < 64; ++i) {
    int tt = t0 + i;
    cur_arr[tt] = state;
    unsigned int nx = (f[i] >> (3 * state)) & 7u;
    d_out[131072 + tt] = (float)nx;  // traj_zones as float
    state = nx;
  }
}

// ---------------- gather: traj_logits[t][z] = constrained[t][cur_t][z] ----------------
__global__ void k_gather(const float* __restrict__ ws, float* __restrict__ d_out) {
  int idx = blockIdx.x * 256 + threadIdx.x;  // < 131072
  const unsigned int* cur_arr = (const unsigned int*)((const char*)ws + WSB_CUR);
  int t = idx >> 3, z = idx & 7;
  unsigned int cur = cur_arr[t];
  d_out[idx] = ws[WS_CONS + (t * 8 + (int)cur) * 8 + z];
}

extern "C" void kernel_launch(void* const* d_in, const int* in_sizes, int n_in,
                              void* d_out, int out_size, void* d_ws, size_t ws_size,
                              hipStream_t stream) {
  const float* pa    = (const float*)d_in[0];
  const float* times = (const float*)d_in[1];
  const float* gum   = (const float*)d_in[2];
  const int*   edge  = (const int*)d_in[3];
  const float* W1  = (const float*)d_in[4];
  const float* b1  = (const float*)d_in[5];
  const float* W2  = (const float*)d_in[6];
  const float* b2  = (const float*)d_in[7];
  const float* W3  = (const float*)d_in[8];
  const float* b3  = (const float*)d_in[9];
  const float* W4  = (const float*)d_in[10];
  const float* b4  = (const float*)d_in[11];
  const float* D1  = (const float*)d_in[12];
  const float* d1v = (const float*)d_in[13];
  const float* D2  = (const float*)d_in[14];
  const float* d2v = (const float*)d_in[15];
  const float* D3  = (const float*)d_in[16];
  const float* d3v = (const float*)d_in[17];
  const float* tau = (const float*)d_in[18];
  float* ws = (float*)d_ws;
  float* out = (float*)d_out;

  hipFuncSetAttribute((const void*)k_phaseB,
                      hipFuncAttributeMaxDynamicSharedMemorySize, 98304);

  k_setup<<<1, 256, 0, stream>>>(pa, W1, b1, D1, d1v, W4, D3, edge, ws);
  k_transpose<<<192, 256, 0, stream>>>(W2, W3, D2, ws);
  k_diversity<<<256, 256, 0, stream>>>(times, d2v, d3v, ws);
  k_phaseB<<<2048, 512, 98304, stream>>>(times, W1, b2, b3, b4, gum, tau, ws);
  k_phaseC<<<1, 256, 0, stream>>>(ws, out);
  k_gather<<<512, 256, 0, stream>>>(ws, out);
}

// Round 2
// 195.874 us; speedup vs baseline: 1.7336x; 1.7336x over previous
//
#include <hip/hip_runtime.h>
#include <cstdint>

#define T_STEPS 16384

// ---- workspace float offsets ----
#define WS_U    0         // 256
#define WS_V    256       // 256
#define WS_UDC  512       // 128
#define WS_VDC  640       // 128
#define WS_A    768       // 64
#define WS_PEN  832       // 64
#define WS_W4T  896       // 512 (64x8)
#define WS_D3T  1408      // 512 (64x8)
#define WS_W2T  2048      // 32768 (256x128)
#define WS_W3T  34816     // 8192  (128x64)
#define WS_D2T  43008     // 8192  (128x64)
#define WS_DV   51200     // 131072 (16384x8)
#define WS_G    182272    // 131072 (16384x8) precomputed gumbels
#define WS_CONS 313344    // 1048576 (16384x8x8)
#define WS_END_F 1361920
// byte offsets after the float region
#define WSB_NXT8 (WS_END_F * 4)          // 131072 bytes (u8 nxt[t][c])
#define WSB_CUR  (WSB_NXT8 + 131072)     // 65536 bytes (u32 cur[t])

__device__ __forceinline__ unsigned int fn_compose(unsigned int hi, unsigned int lo) {
  unsigned int r = 0;
  #pragma unroll
  for (int x = 0; x < 8; ++x) {
    unsigned int m = (lo >> (3 * x)) & 7u;
    r |= ((hi >> (3 * m)) & 7u) << (3 * x);
  }
  return r;
}

// ---------------- setup: u,v,udc,vdc,A,pen,W4T,D3T ----------------
__global__ void k_setup(const float* __restrict__ pa, const float* __restrict__ W1,
                        const float* __restrict__ b1, const float* __restrict__ D1,
                        const float* __restrict__ d1, const float* __restrict__ W4,
                        const float* __restrict__ D3, const int* __restrict__ edge,
                        float* __restrict__ ws) {
  int tid = threadIdx.x;  // 256
  {
    int k = tid;
    float acc = b1[k];
    #pragma unroll
    for (int i = 0; i < 8; ++i) acc = fmaf(pa[i], W1[k * 17 + i], acc);
    ws[WS_U + k] = acc;
    ws[WS_V + k] = W1[k * 17 + 8];
  }
  if (tid < 128) {
    float acc = d1[tid];
    #pragma unroll
    for (int i = 0; i < 8; ++i) acc = fmaf(pa[i], D1[tid * 9 + i], acc);
    ws[WS_UDC + tid] = acc;
    ws[WS_VDC + tid] = D1[tid * 9 + 8];
  }
  if (tid < 64) ws[WS_A + tid] = ((tid >> 3) == (tid & 7)) ? 1.0f : 0.0f;
  for (int idx = tid; idx < 512; idx += 256) {
    int k = idx >> 3, z = idx & 7;
    ws[WS_W4T + idx] = W4[z * 64 + k];
    ws[WS_D3T + idx] = D3[z * 64 + k];
  }
  __syncthreads();
  if (tid == 0) {
    for (int e = 0; e < 16; ++e) {
      int a = edge[e], b = edge[16 + e];
      ws[WS_A + a * 8 + b] = 1.0f;
      ws[WS_A + b * 8 + a] = 1.0f;
    }
  }
  __syncthreads();
  if (tid < 64) ws[WS_PEN + tid] = 1000.0f * (1.0f - ws[WS_A + tid]);
}

// ---------------- transposes + gumbel precompute ----------------
__global__ void k_prep(const float* __restrict__ W2, const float* __restrict__ W3,
                       const float* __restrict__ D2, const float* __restrict__ gum,
                       float* __restrict__ ws) {
  int idx = blockIdx.x * 256 + threadIdx.x;
  if (idx < 32768) {
    int j = idx >> 8, k = idx & 255;
    ws[WS_W2T + k * 128 + j] = W2[idx];
  } else if (idx < 40960) {
    int i = idx - 32768;
    int j = i >> 7, k = i & 127;
    ws[WS_W3T + k * 64 + j] = W3[i];
  } else if (idx < 49152) {
    int i = idx - 40960;
    int j = i >> 7, k = i & 127;
    ws[WS_D2T + k * 64 + j] = D2[i];
  } else {
    int i = idx - 49152;  // < 131072
    float uu = gum[i];
    ws[WS_G + i] = -logf(-logf(uu + 1e-20f) + 1e-20f);
  }
}

// ---------------- diversity network: dv[t][8] ----------------
__global__ void __launch_bounds__(256) k_diversity(
    const float* __restrict__ times, const float* __restrict__ d2,
    const float* __restrict__ d3, float* __restrict__ ws) {
  __shared__ float h1dT[128][64];  // 32KB
  __shared__ float h2dT[64][64];   // 16KB
  int tid = threadIdx.x;
  int s = tid & 63, w = tid >> 6;
  int t = blockIdx.x * 64 + s;
  float last = times[T_STEPS - 1];
  float st = (last > 0.0f) ? times[t] / last : 0.0f;
  int j0 = __builtin_amdgcn_readfirstlane(w * 32);
  #pragma unroll
  for (int jj = 0; jj < 32; ++jj) {
    int j = j0 + jj;
    h1dT[j][s] = fmaxf(fmaf(st, ws[WS_VDC + j], ws[WS_UDC + j]), 0.0f);
  }
  __syncthreads();
  j0 = __builtin_amdgcn_readfirstlane(w * 16);
  float acc[16];
  #pragma unroll
  for (int jj = 0; jj < 16; ++jj) acc[jj] = d2[j0 + jj];
  #pragma unroll 4
  for (int k = 0; k < 128; ++k) {
    float h = h1dT[k][s];
    #pragma unroll
    for (int jj = 0; jj < 16; ++jj)
      acc[jj] = fmaf(ws[WS_D2T + k * 64 + j0 + jj], h, acc[jj]);
  }
  #pragma unroll
  for (int jj = 0; jj < 16; ++jj) h2dT[j0 + jj][s] = fmaxf(acc[jj], 0.0f);
  __syncthreads();
  if (tid < 64) {
    float a8[8];
    #pragma unroll
    for (int z = 0; z < 8; ++z) a8[z] = d3[z];
    #pragma unroll 4
    for (int k = 0; k < 64; ++k) {
      float h = h2dT[k][s];
      #pragma unroll
      for (int z = 0; z < 8; ++z) a8[z] = fmaf(ws[WS_D3T + k * 8 + z], h, a8[z]);
    }
    #pragma unroll
    for (int z = 0; z < 8; ++z) ws[WS_DV + t * 8 + z] = tanhf(a8[z]);
  }
}

// ---------------- phase B: all (t, c) MLP evals, 40KB LDS, 4 blocks/CU ----------------
__global__ void __launch_bounds__(512, 8) k_phaseB(
    const float* __restrict__ times, const float* __restrict__ W1,
    const float* __restrict__ b2, const float* __restrict__ b3,
    const float* __restrict__ b4,
    const float* __restrict__ u_, const float* __restrict__ v_,
    const float* __restrict__ w2t, const float* __restrict__ w3t,
    const float* __restrict__ w4t, const float* __restrict__ dv,
    const float* __restrict__ gt, const float* __restrict__ pen,
    const float* __restrict__ tau,
    float* __restrict__ cons_out, unsigned char* __restrict__ nxt_out) {
  __shared__ float s_w1z[2048];     // [k][c]; first 512 reused for W4T later
  __shared__ float s_h2[128 * 64];  // h2T; rows 0..63 reused for h3T
  int tid = threadIdx.x;
  int s = tid & 63, w = tid >> 6;  // lane = sample (tt*8 + c), 8 waves
  int t0 = blockIdx.x * 8;
  int t = t0 + (s >> 3);
  int c = s & 7;

  // stage W1z into LDS
  #pragma unroll
  for (int e = tid; e < 2048; e += 512)
    s_w1z[e] = W1[(e >> 3) * 17 + 9 + (e & 7)];

  float last = times[T_STEPS - 1];
  float st = (last > 0.0f) ? times[t] / last : 0.0f;
  __syncthreads();

  // fused layer1+2: recompute h1[k] per k (3 VALU), 16 FMAs per wave
  int j0 = __builtin_amdgcn_readfirstlane(w * 16);
  float acc[16];
  #pragma unroll
  for (int jj = 0; jj < 16; ++jj) acc[jj] = b2[j0 + jj];
  #pragma unroll 4
  for (int k = 0; k < 256; ++k) {
    float h = fmaxf(fmaf(st, v_[k], u_[k]) + s_w1z[k * 8 + c], 0.0f);
    #pragma unroll
    for (int jj = 0; jj < 16; ++jj)
      acc[jj] = fmaf(w2t[k * 128 + j0 + jj], h, acc[jj]);
  }
  #pragma unroll
  for (int jj = 0; jj < 16; ++jj) s_h2[(j0 + jj) * 64 + s] = fmaxf(acc[jj], 0.0f);
  __syncthreads();  // B1

  // stage W4T into (now dead) s_w1z[0..511]
  if (tid < 512) s_w1z[tid] = w4t[tid];

  // layer 3: wave w -> outputs [w*8, w*8+8)
  int j3 = __builtin_amdgcn_readfirstlane(w * 8);
  float a3[8];
  #pragma unroll
  for (int i = 0; i < 8; ++i) a3[i] = b3[j3 + i];
  #pragma unroll 4
  for (int k = 0; k < 128; ++k) {
    float h = s_h2[k * 64 + s];
    #pragma unroll
    for (int i = 0; i < 8; ++i)
      a3[i] = fmaf(w3t[k * 64 + j3 + i], h, a3[i]);
  }
  __syncthreads();  // B2: all reads of s_h2 done
  #pragma unroll
  for (int i = 0; i < 8; ++i) s_h2[(j3 + i) * 64 + s] = fmaxf(a3[i], 0.0f);
  __syncthreads();  // B3

  // layer 4 + epilogue: all 8 waves; lane l: sample = w*8+(l>>3), z = l&7
  {
    int l = tid & 63;
    int sm = w * 8 + (l >> 3);
    int z = l & 7;
    int c4 = l >> 3;          // c of this sample
    int t4 = t0 + w;          // t of this sample (wave-uniform)
    float a4a = b4[z], a4b = 0.0f;
    #pragma unroll 4
    for (int k = 0; k < 32; ++k) {
      a4a = fmaf(s_h2[k * 64 + sm], s_w1z[k * 8 + z], a4a);
      a4b = fmaf(s_h2[(k + 32) * 64 + sm], s_w1z[(k + 32) * 8 + z], a4b);
    }
    float a4 = a4a + a4b;
    float lg = fmaf(0.2f, dv[t4 * 8 + z], a4) - pen[l];
    float y = (lg + gt[t4 * 8 + z]) / tau[0];
    cons_out[t0 * 64 + w * 64 + l] = lg;  // == ((t4*8+c4)*8+z)
    // argmax over z within each 8-lane group (first-index tie-break)
    float bv = y; int bz = z;
    #pragma unroll
    for (int d = 1; d < 8; d <<= 1) {
      float pv = __shfl_xor(bv, d);
      int pz = __shfl_xor(bz, d);
      if (pv > bv || (pv == bv && pz < bz)) { bv = pv; bz = pz; }
    }
    if (z == 0) nxt_out[t4 * 8 + c4] = (unsigned char)bz;
  }
}

// ---------------- phase C: parallel prefix over transition functions ----------------
__global__ void __launch_bounds__(256) k_phaseC(float* __restrict__ ws, float* __restrict__ d_out) {
  int tid = threadIdx.x;
  const unsigned char* nxt8 = (const unsigned char*)ws + WSB_NXT8;
  unsigned int* cur_arr = (unsigned int*)((char*)ws + WSB_CUR);
  const unsigned int IDENT = 0x00FAC688u;
  unsigned int f[64];
  int t0 = tid * 64;
  unsigned int F = IDENT;
  #pragma unroll
  for (int i = 0; i < 64; ++i) {
    uint2 b = *(const uint2*)(nxt8 + (size_t)(t0 + i) * 8);
    unsigned int fn = 0;
    #pragma unroll
    for (int q = 0; q < 4; ++q) fn |= ((b.x >> (8 * q)) & 7u) << (3 * q);
    #pragma unroll
    for (int q = 0; q < 4; ++q) fn |= ((b.y >> (8 * q)) & 7u) << (3 * (q + 4));
    f[i] = fn;
    F = fn_compose(fn, F);
  }
  __shared__ unsigned int sc[256];
  sc[tid] = F;
  __syncthreads();
  #pragma unroll
  for (int d = 1; d < 256; d <<= 1) {
    unsigned int v = sc[tid];
    unsigned int p = (tid >= d) ? sc[tid - d] : 0u;
    unsigned int nv = (tid >= d) ? fn_compose(v, p) : v;
    __syncthreads();
    sc[tid] = nv;
    __syncthreads();
  }
  unsigned int E = (tid == 0) ? IDENT : sc[tid - 1];
  unsigned int state = E & 7u;
  #pragma unroll
  for (int i = 0; i < 64; ++i) {
    int tt = t0 + i;
    cur_arr[tt] = state;
    unsigned int nx = (f[i] >> (3 * state)) & 7u;
    d_out[131072 + tt] = (float)nx;
    state = nx;
  }
}

// ---------------- gather ----------------
__global__ void k_gather(const float* __restrict__ ws, float* __restrict__ d_out) {
  int idx = blockIdx.x * 256 + threadIdx.x;  // < 131072
  const unsigned int* cur_arr = (const unsigned int*)((const char*)ws + WSB_CUR);
  int t = idx >> 3, z = idx & 7;
  unsigned int cur = cur_arr[t];
  d_out[idx] = ws[WS_CONS + (t * 8 + (int)cur) * 8 + z];
}

extern "C" void kernel_launch(void* const* d_in, const int* in_sizes, int n_in,
                              void* d_out, int out_size, void* d_ws, size_t ws_size,
                              hipStream_t stream) {
  const float* pa    = (const float*)d_in[0];
  const float* times = (const float*)d_in[1];
  const float* gum   = (const float*)d_in[2];
  const int*   edge  = (const int*)d_in[3];
  const float* W1  = (const float*)d_in[4];
  const float* b1  = (const float*)d_in[5];
  const float* W2  = (const float*)d_in[6];
  const float* b2  = (const float*)d_in[7];
  const float* W3  = (const float*)d_in[8];
  const float* b3  = (const float*)d_in[9];
  const float* W4  = (const float*)d_in[10];
  const float* b4  = (const float*)d_in[11];
  const float* D1  = (const float*)d_in[12];
  const float* d1v = (const float*)d_in[13];
  const float* D2  = (const float*)d_in[14];
  const float* d2v = (const float*)d_in[15];
  const float* D3  = (const float*)d_in[16];
  const float* d3v = (const float*)d_in[17];
  const float* tau = (const float*)d_in[18];
  float* ws = (float*)d_ws;
  float* out = (float*)d_out;

  k_setup<<<1, 256, 0, stream>>>(pa, W1, b1, D1, d1v, W4, D3, edge, ws);
  k_prep<<<704, 256, 0, stream>>>(W2, W3, D2, gum, ws);
  k_diversity<<<256, 256, 0, stream>>>(times, d2v, d3v, ws);
  k_phaseB<<<2048, 512, 0, stream>>>(times, W1, b2, b3, b4,
                                     ws + WS_U, ws + WS_V, ws + WS_W2T, ws + WS_W3T,
                                     ws + WS_W4T, ws + WS_DV, ws + WS_G, ws + WS_PEN,
                                     tau, ws + WS_CONS,
                                     (unsigned char*)ws + WSB_NXT8);
  k_phaseC<<<1, 256, 0, stream>>>(ws, out);
  k_gather<<<512, 256, 0, stream>>>(ws, out);
}